// Round 7
// baseline (6814.036 us; speedup 1.0000x reference)
//
#include <hip/hip_runtime.h>
#include <math.h>

#define B_  32
#define S_  512
#define H_  1024
#define G3_ 3072

typedef __attribute__((ext_vector_type(8))) short bf16x8;   // 8 bf16 in 4 VGPRs
typedef __attribute__((ext_vector_type(4))) float f32x4;

__device__ __forceinline__ unsigned short f2bf(float f) {
  unsigned int u = __float_as_uint(f);
  u = (u + 0x7FFFu + ((u >> 16) & 1u)) >> 16;   // RNE
  return (unsigned short)u;
}
__device__ __forceinline__ float bf2f(unsigned short h) {
  return __uint_as_float(((unsigned int)h) << 16);
}

__global__ void cast_f32_bf16(const float* __restrict__ in, unsigned short* __restrict__ out, int n) {
  int i = blockIdx.x * 256 + threadIdx.x;
  if (i < n) out[i] = f2bf(in[i]);
}

// ---------------- big GEMM (unchanged, verified in R1/R3/R5) ----------------
template<int APERM, int CPERM, typename CT>
__global__ __launch_bounds__(256)
void gemm_bf16(const unsigned short* __restrict__ A, const unsigned short* __restrict__ W,
               const float* __restrict__ bias, CT* __restrict__ C, int M, int N, int K) {
  __shared__ __align__(16) unsigned short As[128 * 40];
  __shared__ __align__(16) unsigned short Ws[128 * 40];
  const int tid   = threadIdx.x;
  const int mBase = blockIdx.y * 128;
  const int nBase = blockIdx.x * 128;
  const int lane  = tid & 63;
  const int w     = tid >> 6;
  const int wm    = (w & 1) * 64;
  const int wn    = (w >> 1) * 64;
  const int r16   = lane & 15;
  const int q     = lane >> 4;

  f32x4 acc[4][4];
  for (int i = 0; i < 4; ++i)
    for (int j = 0; j < 4; ++j)
      for (int t = 0; t < 4; ++t) acc[i][j][t] = 0.f;

  const int r0  = tid >> 2;
  const int kk0 = (tid & 3) * 8;

  for (int k0 = 0; k0 < K; k0 += 32) {
    {
      int r = r0;
      size_t ar = APERM ? ((size_t)((mBase + r) & 31) * S_ + (size_t)((mBase + r) >> 5)) : (size_t)(mBase + r);
      *(uint4*)&As[r * 40 + kk0] = *(const uint4*)(A + ar * K + k0 + kk0);
      int r2 = r + 64;
      size_t ar2 = APERM ? ((size_t)((mBase + r2) & 31) * S_ + (size_t)((mBase + r2) >> 5)) : (size_t)(mBase + r2);
      *(uint4*)&As[r2 * 40 + kk0] = *(const uint4*)(A + ar2 * K + k0 + kk0);
      *(uint4*)&Ws[r * 40 + kk0]  = *(const uint4*)(W + (size_t)(nBase + r)  * K + k0 + kk0);
      *(uint4*)&Ws[r2 * 40 + kk0] = *(const uint4*)(W + (size_t)(nBase + r2) * K + k0 + kk0);
    }
    __syncthreads();
    bf16x8 af[4], bfr[4];
#pragma unroll
    for (int i = 0; i < 4; ++i) af[i]  = *(const bf16x8*)&As[(wm + i * 16 + r16) * 40 + q * 8];
#pragma unroll
    for (int j = 0; j < 4; ++j) bfr[j] = *(const bf16x8*)&Ws[(wn + j * 16 + r16) * 40 + q * 8];
#pragma unroll
    for (int i = 0; i < 4; ++i)
#pragma unroll
      for (int j = 0; j < 4; ++j)
        acc[i][j] = __builtin_amdgcn_mfma_f32_16x16x32_bf16(af[i], bfr[j], acc[i][j], 0, 0, 0);
    __syncthreads();
  }

#pragma unroll
  for (int i = 0; i < 4; ++i)
#pragma unroll
    for (int j = 0; j < 4; ++j)
#pragma unroll
      for (int t = 0; t < 4; ++t) {
        int m = mBase + wm + i * 16 + q * 4 + t;
        int n = nBase + wn + j * 16 + r16;
        float v = acc[i][j][t] + bias[n];
        size_t crow = CPERM ? ((size_t)(m & 31) * S_ + (size_t)(m >> 5)) : (size_t)m;
        if constexpr (sizeof(CT) == 4) C[crow * N + n] = v;
        else                           C[crow * N + n] = f2bf(v);
      }
}

// ---------------- persistent GRU layer, atomics-only coherence ----------------
// 64 blocks x 256 threads (4 waves). Block owns j-slice [j0,j0+16) of all 3 gates.
// Wave w: K-slice [w*256,(w+1)*256). Whh B-frags in registers (loaded once).
// __launch_bounds__(256,1): 1 wave/EU -> full 512-VGPR budget. bw(96)+a0a1(64)
// +acc(24) must stay register-resident; at default bounds the compiler spilled
// bw to scratch and re-loaded it every step (R5/R6: VGPR_Count 104/128, ~6us/step).

template<typename XPT>
__global__ __launch_bounds__(256, 1)
void gru_layer(const unsigned short* __restrict__ Whh, const XPT* __restrict__ xp,
               const unsigned short* __restrict__ h0b,
               unsigned short* __restrict__ y, float* __restrict__ hlast,
               unsigned int* __restrict__ ctrs) {
  __shared__ __align__(16) float part[4 * 6 * 64 * 4];   // 24 KB: [w][tile(m,g)][lane][reg]
  const int tid  = threadIdx.x;
  const int lane = tid & 63;
  const int w    = tid >> 6;          // K-slice id
  const int r16  = lane & 15;
  const int q    = lane >> 4;
  const int j0   = blockIdx.x * 16;

  // Whh B-frags -> registers (once). bw[g][c]: lane(r16,q) holds W[g*H+j0+r16][w*256+c*32+q*8..+8]
  bf16x8 bw[3][8];
#pragma unroll
  for (int g = 0; g < 3; ++g)
#pragma unroll
    for (int c = 0; c < 8; ++c)
      bw[g][c] = *(const bf16x8*)(Whh + (size_t)(g * H_ + j0 + r16) * H_ + w * 256 + c * 32 + q * 8);

  // fp32 h state, block-private, register-resident.
  // epilogue mapping: v in {0,1}, e in {0,1}: o2 = v*128+tid, b = o2>>3, j = (o2&7)*2+e
  float phv[4] = {0.f, 0.f, 0.f, 0.f};

  for (int t = 0; t < S_; ++t) {
    if (t) {                          // wait for all blocks to finish step t-1
      if (w == 0) {
        unsigned tgt = (unsigned)t * 64u;
        int spins = 0;
        for (;;) {
          unsigned v = (lane < 8)
            ? __hip_atomic_load(&ctrs[lane * 16], __ATOMIC_RELAXED, __HIP_MEMORY_SCOPE_AGENT) : 0u;
          v += __shfl_xor(v, 1); v += __shfl_xor(v, 2); v += __shfl_xor(v, 4);
          v = __shfl(v, 0);
          if (v >= tgt) break;
          if (++spins > 32768) break;     // escape hatch: wrong answer beats a hang
          __builtin_amdgcn_s_sleep(1);
        }
      }
      __syncthreads();
      __atomic_signal_fence(__ATOMIC_SEQ_CST);
    }
    const unsigned short* hp = t ? y + (size_t)(t - 1) * (B_ * H_) : h0b;

    // 1) A-frags via agent-scope u64 atomic loads (issued first; pipelined)
    union AU { unsigned long long qq[2]; bf16x8 v; };
    AU a0[8], a1[8];
    {
      unsigned long long* pa0 = (unsigned long long*)(hp + (size_t)r16 * H_ + w * 256 + q * 8);
      unsigned long long* pa1 = (unsigned long long*)(hp + (size_t)(16 + r16) * H_ + w * 256 + q * 8);
#pragma unroll
      for (int c = 0; c < 8; ++c) {
        a0[c].qq[0] = __hip_atomic_load(pa0 + c * 8,     __ATOMIC_RELAXED, __HIP_MEMORY_SCOPE_AGENT);
        a0[c].qq[1] = __hip_atomic_load(pa0 + c * 8 + 1, __ATOMIC_RELAXED, __HIP_MEMORY_SCOPE_AGENT);
        a1[c].qq[0] = __hip_atomic_load(pa1 + c * 8,     __ATOMIC_RELAXED, __HIP_MEMORY_SCOPE_AGENT);
        a1[c].qq[1] = __hip_atomic_load(pa1 + c * 8 + 1, __ATOMIC_RELAXED, __HIP_MEMORY_SCOPE_AGENT);
      }
    }
    __atomic_signal_fence(__ATOMIC_SEQ_CST);   // keep xp loads AFTER h loads (issue order)

    // 2) xp loads for THIS step — latency hides under MFMA + LDS reduce
    float pxr[4], pxz[4], pxn[4];
    if (tid < 128) {
      const XPT* xt = xp + (size_t)t * (B_ * G3_);
#pragma unroll
      for (int v = 0; v < 2; ++v) {
        int o2 = v * 128 + tid, b = o2 >> 3, j = (o2 & 7) * 2;
#pragma unroll
        for (int e = 0; e < 2; ++e) {
          const XPT* x0 = xt + (size_t)b * G3_ + j0 + j + e;
          if constexpr (sizeof(XPT) == 4) {
            pxr[v * 2 + e] = x0[0]; pxz[v * 2 + e] = x0[H_]; pxn[v * 2 + e] = x0[2 * H_];
          } else {
            pxr[v * 2 + e] = bf2f(x0[0]); pxz[v * 2 + e] = bf2f(x0[H_]); pxn[v * 2 + e] = bf2f(x0[2 * H_]);
          }
        }
      }
    }

    f32x4 acc[2][3];
#pragma unroll
    for (int m = 0; m < 2; ++m)
#pragma unroll
      for (int g = 0; g < 3; ++g)
#pragma unroll
        for (int u = 0; u < 4; ++u) acc[m][g][u] = 0.f;

#pragma unroll
    for (int c = 0; c < 8; ++c)
#pragma unroll
      for (int g = 0; g < 3; ++g) {
        acc[0][g] = __builtin_amdgcn_mfma_f32_16x16x32_bf16(a0[c].v, bw[g][c], acc[0][g], 0, 0, 0);
        acc[1][g] = __builtin_amdgcn_mfma_f32_16x16x32_bf16(a1[c].v, bw[g][c], acc[1][g], 0, 0, 0);
      }

#pragma unroll
    for (int m = 0; m < 2; ++m)
#pragma unroll
      for (int g = 0; g < 3; ++g)
        *(f32x4*)&part[((w * 6 + m * 3 + g) * 64 + lane) * 4] = acc[m][g];
    __syncthreads();

    if (tid < 128) {
      unsigned short* yt = y + (size_t)t * (B_ * H_);
#pragma unroll
      for (int v = 0; v < 2; ++v) {
        int o2 = v * 128 + tid, b = o2 >> 3, j = (o2 & 7) * 2;
        int m = b >> 4, q2 = (b >> 2) & 3, reg = b & 3;
        float hv2[2];
#pragma unroll
        for (int e = 0; e < 2; ++e) {
          int jj = j + e;
          float hr = 0.f, hz = 0.f, hn = 0.f;
#pragma unroll
          for (int ww = 0; ww < 4; ++ww) {
            int baseT = ww * 6 + m * 3;
            hr += part[((baseT + 0) * 64 + q2 * 16 + jj) * 4 + reg];
            hz += part[((baseT + 1) * 64 + q2 * 16 + jj) * 4 + reg];
            hn += part[((baseT + 2) * 64 + q2 * 16 + jj) * 4 + reg];
          }
          int pi = v * 2 + e;
          // fast sigmoid/tanh: __expf + v_rcp (absmax slack ~2.4x, drift negligible)
          float r  = __builtin_amdgcn_rcpf(1.f + __expf(-(pxr[pi] + hr)));
          float z  = __builtin_amdgcn_rcpf(1.f + __expf(-(pxz[pi] + hz)));
          float a2 = pxn[pi] + hn + r * hn;
          float nn = 1.f - 2.f * __builtin_amdgcn_rcpf(__expf(2.f * a2) + 1.f);  // tanh
          float hv = (1.f - z) * nn + z * phv[pi];
          phv[pi] = hv;
          hv2[e] = hv;
        }
        unsigned int pk = (unsigned int)f2bf(hv2[0]) | ((unsigned int)f2bf(hv2[1]) << 16);
        __hip_atomic_store((unsigned int*)(yt + (size_t)b * H_ + j0 + j), pk,
                           __ATOMIC_RELAXED, __HIP_MEMORY_SCOPE_AGENT);
        if (t == S_ - 1) {
          hlast[b * H_ + j0 + j]     = hv2[0];
          hlast[b * H_ + j0 + j + 1] = hv2[1];
        }
      }
    }
    __atomic_signal_fence(__ATOMIC_SEQ_CST);
    __syncthreads();                 // each wave drains vmcnt -> y stores at coherence point
    if (tid == 0)
      __hip_atomic_fetch_add(&ctrs[(blockIdx.x & 7) * 16], 1u,
                             __ATOMIC_RELAXED, __HIP_MEMORY_SCOPE_AGENT);
  }
}

extern "C" void kernel_launch(void* const* d_in, const int* in_sizes, int n_in,
                              void* d_out, int out_size, void* d_ws, size_t ws_size,
                              hipStream_t stream) {
  const float* x    = (const float*)d_in[0];
  const float* Wih0 = (const float*)d_in[1];
  const float* Whh0 = (const float*)d_in[2];
  const float* b0   = (const float*)d_in[3];
  const float* Wih1 = (const float*)d_in[4];
  const float* Whh1 = (const float*)d_in[5];
  const float* b1   = (const float*)d_in[6];
  const float* Wlin = (const float*)d_in[7];
  const float* blin = (const float*)d_in[8];
  float* out = (float*)d_out;

  const bool xpf32 = ws_size >= (size_t)308741120;
  char* p = (char*)d_ws;
  size_t off = 0;
  auto alloc = [&](size_t bytes) { void* r = p + off; off += (bytes + 255) & ~(size_t)255; return r; };

  void* xp = alloc(xpf32 ? (size_t)16384 * G3_ * 4 : (size_t)16384 * G3_ * 2);
  unsigned short* xb    = (unsigned short*)alloc((size_t)8388608 * 2);
  unsigned short* wih0b = (unsigned short*)alloc((size_t)1572864 * 2);
  unsigned short* whh0b = (unsigned short*)alloc((size_t)3145728 * 2);
  unsigned short* wih1b = (unsigned short*)alloc((size_t)3145728 * 2);
  unsigned short* whh1b = (unsigned short*)alloc((size_t)3145728 * 2);
  unsigned short* wlinb = (unsigned short*)alloc((size_t)524288 * 2);
  unsigned short* y0b   = (unsigned short*)alloc((size_t)16777216 * 2);  // (S,B,H) bf16
  unsigned short* y1b   = (unsigned short*)alloc((size_t)16777216 * 2);
  unsigned short* zerosB= (unsigned short*)alloc((size_t)B_ * H_ * 2);
  unsigned int* ctrs0   = (unsigned int*)alloc(512);
  unsigned int* ctrs1   = (unsigned int*)alloc(512);

  (void)hipMemsetAsync(zerosB, 0, (size_t)B_ * H_ * 2, stream);
  (void)hipMemsetAsync(ctrs0, 0, 512, stream);
  (void)hipMemsetAsync(ctrs1, 0, 512, stream);

  auto cast = [&](const float* in, unsigned short* o, int n) {
    cast_f32_bf16<<<n / 256, 256, 0, stream>>>(in, o, n);
  };
  cast(x, xb, 8388608);
  cast(Wih0, wih0b, 1572864);
  cast(Whh0, whh0b, 3145728);
  cast(Wih1, wih1b, 3145728);
  cast(Whh1, whh1b, 3145728);
  cast(Wlin, wlinb, 524288);

  float* hlast0 = out + 8388608;
  float* hlast1 = out + 8388608 + B_ * H_;

  // xproj0: (16384 x 3072 x 512), A = x batch-major (perm), C time-major
  {
    dim3 g(G3_ / 128, 16384 / 128);
    if (xpf32) gemm_bf16<1, 0, float><<<g, 256, 0, stream>>>(xb, wih0b, b0, (float*)xp, 16384, G3_, 512);
    else       gemm_bf16<1, 0, unsigned short><<<g, 256, 0, stream>>>(xb, wih0b, b0, (unsigned short*)xp, 16384, G3_, 512);
  }

  if (xpf32) gru_layer<float><<<64, 256, 0, stream>>>(whh0b, (const float*)xp, zerosB, y0b, hlast0, ctrs0);
  else       gru_layer<unsigned short><<<64, 256, 0, stream>>>(whh0b, (const unsigned short*)xp, zerosB, y0b, hlast0, ctrs0);

  // xproj1: (16384 x 3072 x 1024), A = y0b time-major
  {
    dim3 g(G3_ / 128, 16384 / 128);
    if (xpf32) gemm_bf16<0, 0, float><<<g, 256, 0, stream>>>(y0b, wih1b, b1, (float*)xp, 16384, G3_, 1024);
    else       gemm_bf16<0, 0, unsigned short><<<g, 256, 0, stream>>>(y0b, wih1b, b1, (unsigned short*)xp, 16384, G3_, 1024);
  }

  if (xpf32) gru_layer<float><<<64, 256, 0, stream>>>(whh1b, (const float*)xp, zerosB, y1b, hlast1, ctrs1);
  else       gru_layer<unsigned short><<<64, 256, 0, stream>>>(whh1b, (const unsigned short*)xp, zerosB, y1b, hlast1, ctrs1);

  // final: out = y1 @ Wlin^T + blin, C rows -> (b,s)
  {
    dim3 g(512 / 128, 16384 / 128);
    gemm_bf16<0, 1, float><<<g, 256, 0, stream>>>(y1b, wlinb, blin, out, 16384, 512, 1024);
  }
}

// Round 8
// 4988.415 us; speedup vs baseline: 1.3660x; 1.3660x over previous
//
#include <hip/hip_runtime.h>
#include <math.h>

#define B_  32
#define S_  512
#define H_  1024
#define G3_ 3072

typedef __attribute__((ext_vector_type(8))) short bf16x8;   // 8 bf16 in 4 VGPRs
typedef __attribute__((ext_vector_type(4))) float f32x4;

__device__ __forceinline__ unsigned short f2bf(float f) {
  unsigned int u = __float_as_uint(f);
  u = (u + 0x7FFFu + ((u >> 16) & 1u)) >> 16;   // RNE
  return (unsigned short)u;
}
__device__ __forceinline__ float bf2f(unsigned short h) {
  return __uint_as_float(((unsigned int)h) << 16);
}

__global__ void cast_f32_bf16(const float* __restrict__ in, unsigned short* __restrict__ out, int n) {
  int i = blockIdx.x * 256 + threadIdx.x;
  if (i < n) out[i] = f2bf(in[i]);
}

// x (B,S,512) fp32 -> xtm (S,B,512) bf16
__global__ void cast_transpose_x(const float* __restrict__ x, unsigned short* __restrict__ xtm) {
  int s = blockIdx.x & 511, b = blockIdx.x >> 9;   // grid 16384
  int k = threadIdx.x * 4;                          // 128 threads
  float4 v = *(const float4*)(x + ((size_t)b * S_ + s) * 512 + k);
  ushort4 o = { f2bf(v.x), f2bf(v.y), f2bf(v.z), f2bf(v.w) };
  *(ushort4*)(xtm + ((size_t)s * B_ + b) * 512 + k) = o;
}

// ---------------- big GEMM (verified; used for final projection) ----------------
template<int APERM, int CPERM, typename CT>
__global__ __launch_bounds__(256)
void gemm_bf16(const unsigned short* __restrict__ A, const unsigned short* __restrict__ W,
               const float* __restrict__ bias, CT* __restrict__ C, int M, int N, int K) {
  __shared__ __align__(16) unsigned short As[128 * 40];
  __shared__ __align__(16) unsigned short Ws[128 * 40];
  const int tid   = threadIdx.x;
  const int mBase = blockIdx.y * 128;
  const int nBase = blockIdx.x * 128;
  const int lane  = tid & 63;
  const int w     = tid >> 6;
  const int wm    = (w & 1) * 64;
  const int wn    = (w >> 1) * 64;
  const int r16   = lane & 15;
  const int q     = lane >> 4;

  f32x4 acc[4][4];
  for (int i = 0; i < 4; ++i)
    for (int j = 0; j < 4; ++j)
      for (int t = 0; t < 4; ++t) acc[i][j][t] = 0.f;

  const int r0  = tid >> 2;
  const int kk0 = (tid & 3) * 8;

  for (int k0 = 0; k0 < K; k0 += 32) {
    {
      int r = r0;
      size_t ar = APERM ? ((size_t)((mBase + r) & 31) * S_ + (size_t)((mBase + r) >> 5)) : (size_t)(mBase + r);
      *(uint4*)&As[r * 40 + kk0] = *(const uint4*)(A + ar * K + k0 + kk0);
      int r2 = r + 64;
      size_t ar2 = APERM ? ((size_t)((mBase + r2) & 31) * S_ + (size_t)((mBase + r2) >> 5)) : (size_t)(mBase + r2);
      *(uint4*)&As[r2 * 40 + kk0] = *(const uint4*)(A + ar2 * K + k0 + kk0);
      *(uint4*)&Ws[r * 40 + kk0]  = *(const uint4*)(W + (size_t)(nBase + r)  * K + k0 + kk0);
      *(uint4*)&Ws[r2 * 40 + kk0] = *(const uint4*)(W + (size_t)(nBase + r2) * K + k0 + kk0);
    }
    __syncthreads();
    bf16x8 af[4], bfr[4];
#pragma unroll
    for (int i = 0; i < 4; ++i) af[i]  = *(const bf16x8*)&As[(wm + i * 16 + r16) * 40 + q * 8];
#pragma unroll
    for (int j = 0; j < 4; ++j) bfr[j] = *(const bf16x8*)&Ws[(wn + j * 16 + r16) * 40 + q * 8];
#pragma unroll
    for (int i = 0; i < 4; ++i)
#pragma unroll
      for (int j = 0; j < 4; ++j)
        acc[i][j] = __builtin_amdgcn_mfma_f32_16x16x32_bf16(af[i], bfr[j], acc[i][j], 0, 0, 0);
    __syncthreads();
  }

#pragma unroll
  for (int i = 0; i < 4; ++i)
#pragma unroll
    for (int j = 0; j < 4; ++j)
#pragma unroll
      for (int t = 0; t < 4; ++t) {
        int m = mBase + wm + i * 16 + q * 4 + t;
        int n = nBase + wn + j * 16 + r16;
        float v = acc[i][j][t] + bias[n];
        size_t crow = CPERM ? ((size_t)(m & 31) * S_ + (size_t)(m >> 5)) : (size_t)m;
        if constexpr (sizeof(CT) == 4) C[crow * N + n] = v;
        else                           C[crow * N + n] = f2bf(v);
      }
}

// ---------------- fused 2-layer persistent GRU, pipelined ----------------
// 128 blocks x 512 threads (8 waves). Blocks 0-63: layer 0; 64-127: layer 1
// (trailing one step). Block owns j-slice [j0,j0+16) of all 3 gates.
// K = concat[x-part ; h-part]: waves 0-3 cover the x-part (L0: x[t] K=512,
// L1: y0[t] K=1024), waves 4-7 the h-part (own layer's h[t-1], K=1024).
// The n-gate's x/h partials stay separate (reference: tanh(nx+bn+nh+r*nh)).
// Cross-block h/y via agent-scope relaxed atomics (proven R3/R5 mechanism);
// two monotonic counter groups; layer 1 polls both. 513 serial barrier-steps.

__global__ __launch_bounds__(512, 2)
void gru_fused(const unsigned short* __restrict__ wih0, const unsigned short* __restrict__ whh0,
               const float* __restrict__ b0,
               const unsigned short* __restrict__ wih1, const unsigned short* __restrict__ whh1,
               const float* __restrict__ b1,
               const unsigned short* __restrict__ xtm, const unsigned short* __restrict__ zerosB,
               unsigned short* __restrict__ y0, unsigned short* __restrict__ y1,
               float* __restrict__ hlast0, float* __restrict__ hlast1,
               unsigned int* __restrict__ ctr0, unsigned int* __restrict__ ctr1) {
  __shared__ __align__(16) float part[8 * 2 * 3 * 64 * 4];   // 48 KB [w][m][g][lane][reg]
  const int tid  = threadIdx.x;
  const int lane = tid & 63;
  const int w    = tid >> 6;          // 0..7
  const int r16  = lane & 15;
  const int q    = lane >> 4;
  const bool L1  = blockIdx.x >= 64;
  const int  j0  = (L1 ? (int)blockIdx.x - 64 : (int)blockIdx.x) * 16;
  const bool hiw = w >= 4;

  // per-wave operand plan
  const unsigned short* Wsrc;
  int wstride, kbase, ncha;
  if (!L1) {
    if (!hiw) { Wsrc = wih0; wstride = 512;  kbase = w * 128;       ncha = 4; }
    else      { Wsrc = whh0; wstride = 1024; kbase = (w - 4) * 256; ncha = 8; }
  } else {
    if (!hiw) { Wsrc = wih1; wstride = 1024; kbase = w * 256;       ncha = 8; }
    else      { Wsrc = whh1; wstride = 1024; kbase = (w - 4) * 256; ncha = 8; }
  }

  // B-frags -> registers, once
  bf16x8 bw[3][8];
#pragma unroll
  for (int g = 0; g < 3; ++g)
#pragma unroll
    for (int c = 0; c < 8; ++c)
      if (c < ncha)
        bw[g][c] = *(const bf16x8*)(Wsrc + (size_t)(g * H_ + j0 + r16) * wstride + kbase + c * 32 + q * 8);

  const float* bias = L1 ? b1 : b0;
  float br[2], bz[2], bn[2], phv[2] = {0.f, 0.f};
  if (tid < 256) {
    int jj = j0 + (tid & 7) * 2;
#pragma unroll
    for (int e = 0; e < 2; ++e) {
      br[e] = bias[jj + e]; bz[e] = bias[H_ + jj + e]; bn[e] = bias[2 * H_ + jj + e];
    }
  }

  unsigned short* ybuf = L1 ? y1 : y0;
  unsigned int*  ctrM  = L1 ? ctr1 : ctr0;
  float*         hlast = L1 ? hlast1 : hlast0;

  for (int t = 0; t < S_; ++t) {
    // ---- wait for dependencies ----
    if (w == 0) {
      if (!L1) {
        if (t) {
          unsigned tgt = 64u * (unsigned)t; int spins = 0;
          for (;;) {
            unsigned v = (lane < 8)
              ? __hip_atomic_load(&ctr0[lane * 16], __ATOMIC_RELAXED, __HIP_MEMORY_SCOPE_AGENT) : 0u;
            v += __shfl_xor(v, 1); v += __shfl_xor(v, 2); v += __shfl_xor(v, 4);
            if (__shfl(v, 0) >= tgt) break;
            if (++spins > 65536) break;
            __builtin_amdgcn_s_sleep(1);
          }
        }
      } else {
        unsigned tgt0 = 64u * (unsigned)(t + 1), tgt1 = 64u * (unsigned)t; int spins = 0;
        for (;;) {
          unsigned v = 0u;
          if (lane < 8)       v = __hip_atomic_load(&ctr0[lane * 16],       __ATOMIC_RELAXED, __HIP_MEMORY_SCOPE_AGENT);
          else if (lane < 16) v = __hip_atomic_load(&ctr1[(lane - 8) * 16], __ATOMIC_RELAXED, __HIP_MEMORY_SCOPE_AGENT);
          v += __shfl_xor(v, 1); v += __shfl_xor(v, 2); v += __shfl_xor(v, 4);
          unsigned s0 = __shfl(v, 0), s1 = __shfl(v, 8);
          if (s0 >= tgt0 && (t == 0 || s1 >= tgt1)) break;
          if (++spins > 65536) break;
          __builtin_amdgcn_s_sleep(1);
        }
      }
    }
    __syncthreads();
    __atomic_signal_fence(__ATOMIC_SEQ_CST);

    // ---- A-frags ----
    const unsigned short* Asrc;
    int astride; bool plainA;
    if (!hiw) {
      if (!L1) { Asrc = xtm + (size_t)t * B_ * 512; astride = 512;  plainA = true; }
      else     { Asrc = y0  + (size_t)t * B_ * H_;  astride = 1024; plainA = false; }
    } else {
      Asrc = t ? ybuf + (size_t)(t - 1) * B_ * H_ : zerosB; astride = 1024; plainA = (t == 0);
    }
    union AU { unsigned long long qq[2]; bf16x8 v; };
    AU a0[8], a1[8];
    const unsigned short* ap0 = Asrc + (size_t)r16 * astride + kbase + q * 8;
    const unsigned short* ap1 = ap0 + 16 * astride;
    if (plainA) {
#pragma unroll
      for (int c = 0; c < 8; ++c) if (c < ncha) {
        a0[c].v = *(const bf16x8*)(ap0 + c * 32);
        a1[c].v = *(const bf16x8*)(ap1 + c * 32);
      }
    } else {
#pragma unroll
      for (int c = 0; c < 8; ++c) if (c < ncha) {
        unsigned long long* p0 = (unsigned long long*)(ap0 + c * 32);
        unsigned long long* p1 = (unsigned long long*)(ap1 + c * 32);
        a0[c].qq[0] = __hip_atomic_load(p0,     __ATOMIC_RELAXED, __HIP_MEMORY_SCOPE_AGENT);
        a0[c].qq[1] = __hip_atomic_load(p0 + 1, __ATOMIC_RELAXED, __HIP_MEMORY_SCOPE_AGENT);
        a1[c].qq[0] = __hip_atomic_load(p1,     __ATOMIC_RELAXED, __HIP_MEMORY_SCOPE_AGENT);
        a1[c].qq[1] = __hip_atomic_load(p1 + 1, __ATOMIC_RELAXED, __HIP_MEMORY_SCOPE_AGENT);
      }
    }

    f32x4 acc[2][3];
#pragma unroll
    for (int m = 0; m < 2; ++m)
#pragma unroll
      for (int g = 0; g < 3; ++g)
#pragma unroll
        for (int u = 0; u < 4; ++u) acc[m][g][u] = 0.f;

#pragma unroll
    for (int c = 0; c < 8; ++c) if (c < ncha)
#pragma unroll
      for (int g = 0; g < 3; ++g) {
        acc[0][g] = __builtin_amdgcn_mfma_f32_16x16x32_bf16(a0[c].v, bw[g][c], acc[0][g], 0, 0, 0);
        acc[1][g] = __builtin_amdgcn_mfma_f32_16x16x32_bf16(a1[c].v, bw[g][c], acc[1][g], 0, 0, 0);
      }

#pragma unroll
    for (int m = 0; m < 2; ++m)
#pragma unroll
      for (int g = 0; g < 3; ++g)
        *(f32x4*)&part[(((w * 2 + m) * 3 + g) * 64 + lane) * 4] = acc[m][g];
    __syncthreads();

    // ---- epilogue: 256 threads x 2 outputs ----
    if (tid < 256) {
      unsigned short* yt = ybuf + (size_t)t * (B_ * H_);
      int b = tid >> 3, jp = (tid & 7) * 2;
      int m = b >> 4, q2 = (b >> 2) & 3, reg = b & 3;
      float hv2[2];
#pragma unroll
      for (int e = 0; e < 2; ++e) {
        int jj = jp + e;
        float hr = 0.f, hz = 0.f, nx = 0.f, nh = 0.f;
#pragma unroll
        for (int ww = 0; ww < 8; ++ww) {
          int base = (ww * 2 + m) * 3;
          float vr = part[((base + 0) * 64 + q2 * 16 + jj) * 4 + reg];
          float vz = part[((base + 1) * 64 + q2 * 16 + jj) * 4 + reg];
          float vn = part[((base + 2) * 64 + q2 * 16 + jj) * 4 + reg];
          hr += vr; hz += vz;
          if (ww < 4) nx += vn; else nh += vn;
        }
        float r  = __builtin_amdgcn_rcpf(1.f + __expf(-(hr + br[e])));
        float z  = __builtin_amdgcn_rcpf(1.f + __expf(-(hz + bz[e])));
        float a2 = nx + bn[e] + nh + r * nh;
        float nn = 1.f - 2.f * __builtin_amdgcn_rcpf(__expf(2.f * a2) + 1.f);  // tanh
        float hv = (1.f - z) * nn + z * phv[e];
        phv[e] = hv; hv2[e] = hv;
      }
      unsigned int pk = (unsigned int)f2bf(hv2[0]) | ((unsigned int)f2bf(hv2[1]) << 16);
      __hip_atomic_store((unsigned int*)(yt + (size_t)b * H_ + j0 + jp), pk,
                         __ATOMIC_RELAXED, __HIP_MEMORY_SCOPE_AGENT);
      if (t == S_ - 1) {
        hlast[b * H_ + j0 + jp]     = hv2[0];
        hlast[b * H_ + j0 + jp + 1] = hv2[1];
      }
    }
    __atomic_signal_fence(__ATOMIC_SEQ_CST);
    __syncthreads();                 // each wave drains vmcnt -> y stores at coherence point
    if (tid == 0)
      __hip_atomic_fetch_add(&ctrM[(blockIdx.x & 7) * 16], 1u,
                             __ATOMIC_RELAXED, __HIP_MEMORY_SCOPE_AGENT);
  }
}

extern "C" void kernel_launch(void* const* d_in, const int* in_sizes, int n_in,
                              void* d_out, int out_size, void* d_ws, size_t ws_size,
                              hipStream_t stream) {
  const float* x    = (const float*)d_in[0];
  const float* Wih0 = (const float*)d_in[1];
  const float* Whh0 = (const float*)d_in[2];
  const float* b0   = (const float*)d_in[3];
  const float* Wih1 = (const float*)d_in[4];
  const float* Whh1 = (const float*)d_in[5];
  const float* b1   = (const float*)d_in[6];
  const float* Wlin = (const float*)d_in[7];
  const float* blin = (const float*)d_in[8];
  float* out = (float*)d_out;

  char* p = (char*)d_ws;
  size_t off = 0;
  auto alloc = [&](size_t bytes) { void* r = p + off; off += (bytes + 255) & ~(size_t)255; return r; };

  unsigned short* xtm   = (unsigned short*)alloc((size_t)8388608 * 2);   // (S,B,512) bf16
  unsigned short* wih0b = (unsigned short*)alloc((size_t)1572864 * 2);
  unsigned short* whh0b = (unsigned short*)alloc((size_t)3145728 * 2);
  unsigned short* wih1b = (unsigned short*)alloc((size_t)3145728 * 2);
  unsigned short* whh1b = (unsigned short*)alloc((size_t)3145728 * 2);
  unsigned short* wlinb = (unsigned short*)alloc((size_t)524288 * 2);
  unsigned short* y0b   = (unsigned short*)alloc((size_t)16777216 * 2);  // (S,B,H) bf16
  unsigned short* y1b   = (unsigned short*)alloc((size_t)16777216 * 2);
  unsigned short* zerosB= (unsigned short*)alloc((size_t)B_ * H_ * 2);
  unsigned int* ctrs0   = (unsigned int*)alloc(512);
  unsigned int* ctrs1   = (unsigned int*)alloc(512);

  (void)hipMemsetAsync(zerosB, 0, (size_t)B_ * H_ * 2, stream);
  (void)hipMemsetAsync(ctrs0, 0, 512, stream);
  (void)hipMemsetAsync(ctrs1, 0, 512, stream);

  auto cast = [&](const float* in, unsigned short* o, int n) {
    cast_f32_bf16<<<n / 256, 256, 0, stream>>>(in, o, n);
  };
  cast_transpose_x<<<16384, 128, 0, stream>>>(x, xtm);
  cast(Wih0, wih0b, 1572864);
  cast(Whh0, whh0b, 3145728);
  cast(Wih1, wih1b, 3145728);
  cast(Whh1, whh1b, 3145728);
  cast(Wlin, wlinb, 524288);

  float* hlast0 = out + 8388608;
  float* hlast1 = out + 8388608 + B_ * H_;

  gru_fused<<<128, 512, 0, stream>>>(wih0b, whh0b, b0, wih1b, whh1b, b1,
                                     xtm, zerosB, y0b, y1b, hlast0, hlast1, ctrs0, ctrs1);

  // final: out = y1 @ Wlin^T + blin, C rows -> (b,s)
  {
    dim3 g(512 / 128, 16384 / 128);
    gemm_bf16<0, 1, float><<<g, 256, 0, stream>>>(y1b, wlinb, blin, out, 16384, 512, 1024);
  }
}